// Round 4
// baseline (210.248 us; speedup 1.0000x reference)
//
#include <hip/hip_runtime.h>
#include <stdint.h>

// Problem constants
#define BB 4
#define CC 256
#define HH 96
#define WW 96
#define HP 98      // halo-padded spatial dim
#define CP 264     // k-stride per x in ush (528 B; measured near-conflict-free b128 frags)
#define XT 32      // x positions per block
#define YT 2       // y rows per block
#define XE 34      // staged x entries (32 + 2 halo)

typedef __bf16 bf16x8 __attribute__((ext_vector_type(8)));
typedef float f32x4 __attribute__((ext_vector_type(4)));
typedef float f32x16 __attribute__((ext_vector_type(16)));

__device__ __forceinline__ uint16_t f2bf(float f) {
    uint32_t u = __float_as_uint(f);
    u += 0x7FFFu + ((u >> 16) & 1u);   // round-to-nearest-even
    return (uint16_t)(u >> 16);
}

// async global->LDS: lane l loads 16 B at g + l*16 B, lands at ldsbase + l*16 B.
// g must therefore be the PER-LANE address (wave-uniform base + lane*8 u16).
__device__ __forceinline__ void gll16(const uint16_t* g, uint16_t* l) {
    __builtin_amdgcn_global_load_lds(
        (const __attribute__((address_space(1))) uint32_t*)g,
        (__attribute__((address_space(3))) uint32_t*)l, 16, 0, 0);
}

// ---------------------------------------------------------------------------
// Pre-kernel 0: zero only the halo strips of cenT (y=0/97 rows, x=0/97 cols).
// ---------------------------------------------------------------------------
__global__ void zero_halo(uint16_t* __restrict__ cenT) {
    int idx = blockIdx.x * 256 + threadIdx.x;          // over 1552 pos * 33 uint4
    if (idx >= 1552 * 33) return;
    int p = idx / 33, q = idx - p * 33;
    int b = p / 388, s = p - b * 388;
    int y, x;
    if (s < 98)      { y = 0;       x = s; }
    else if (s < 196){ y = 97;      x = s - 98; }
    else if (s < 292){ x = 0;       y = s - 196 + 1; }
    else             { x = 97;      y = s - 292 + 1; }
    size_t o = (((size_t)b * HP + y) * HP + x) * CP + q * 8;
    *(uint4*)(cenT + o) = make_uint4(0u, 0u, 0u, 0u);
}

// ---------------------------------------------------------------------------
// Pre-kernel 1: cen (NCHW fp32) -> cenT [b][hy 98][hx 98][264] bf16 (interior).
// ---------------------------------------------------------------------------
__global__ void transpose_cen(const float* __restrict__ cen, uint16_t* __restrict__ cenT) {
    const int y = blockIdx.x, b = blockIdx.y, ch = blockIdx.z, tid = threadIdx.x;
    __shared__ uint16_t ldsX[128 * 100];

    #pragma unroll
    for (int i = 0; i < 12; ++i) {
        int f = i * 256 + tid;            // 0..3071: 128 c x 24 xq
        int c = f / 24, xq = f % 24;
        float4 v = *(const float4*)(cen + ((((size_t)b * CC + ch * 128 + c) * HH + y) * WW + xq * 4));
        uint2 pk;
        pk.x = (uint32_t)f2bf(v.x) | ((uint32_t)f2bf(v.y) << 16);
        pk.y = (uint32_t)f2bf(v.z) | ((uint32_t)f2bf(v.w) << 16);
        *(uint2*)(&ldsX[c * 100 + xq * 4]) = pk;
    }
    __syncthreads();
    #pragma unroll
    for (int i = 0; i < 6; ++i) {
        int t = i * 256 + tid;            // 0..1535: 96 x * 16 cq
        int x = t % 96, cq = t / 96;
        uint32_t w0, w1, w2, w3;
        w0 = (uint32_t)ldsX[(cq * 8 + 0) * 100 + x] | ((uint32_t)ldsX[(cq * 8 + 1) * 100 + x] << 16);
        w1 = (uint32_t)ldsX[(cq * 8 + 2) * 100 + x] | ((uint32_t)ldsX[(cq * 8 + 3) * 100 + x] << 16);
        w2 = (uint32_t)ldsX[(cq * 8 + 4) * 100 + x] | ((uint32_t)ldsX[(cq * 8 + 5) * 100 + x] << 16);
        w3 = (uint32_t)ldsX[(cq * 8 + 6) * 100 + x] | ((uint32_t)ldsX[(cq * 8 + 7) * 100 + x] << 16);
        size_t o = (((size_t)b * HP + (y + 1)) * HP + (x + 1)) * CP + ch * 128 + cq * 8;
        *(uint4*)(cenT + o) = make_uint4(w0, w1, w2, w3);
    }
}

// ---------------------------------------------------------------------------
// Pre-kernel 2: W3 [9][256 n][256 k] fp32 -> W3bf, LANE-LINEAR frag blocks:
// for (g, t=n>>5, ks=k>>4) a 1 KiB block; within it lane (col=n&31, kh=(k>>3)&1)
// holds its 8 bf16 at byte offset lane*16 (lane = kh*32+col).  One gll16 issue
// (per-lane source g + lane*16 B) == one frag block, LDS lands lane-linear,
// and the ds_read_b128 back is the standard conflict-free linear pattern.
// ---------------------------------------------------------------------------
__global__ void cvt_w3(const float* __restrict__ W3, uint16_t* __restrict__ W3bf) {
    int e = (blockIdx.x * 256 + threadIdx.x) * 4;   // 0..589823
    int g = e >> 16, n = (e >> 8) & 255, k = e & 255;
    float4 v = *(const float4*)(W3 + e);
    uint2 pk;
    pk.x = (uint32_t)f2bf(v.x) | ((uint32_t)f2bf(v.y) << 16);
    pk.y = (uint32_t)f2bf(v.z) | ((uint32_t)f2bf(v.w) << 16);
    size_t o = (size_t)(((g * 8 + (n >> 5)) * 16 + (k >> 4)) * 512)
             + ((k >> 3) & 1) * 256 + (n & 31) * 8 + (k & 7);
    *(uint2*)(W3bf + o) = pk;
}

// ---------------------------------------------------------------------------
// Main kernel: grid (3 xt, 48 yt, 4 b) = 576 blocks, 256 thr (4 waves).
// Block tile: 64 positions (2 rows x 32 x) x 256 ch; wave wv owns ch-tiles
// (2wv, 2wv+1).  A (W3 frags) staged through LDS with an async
// global_load_lds DOUBLE BUFFER (2 x 16 KiB = one 2-ks "pair" each):
//   phase p (8 per g): __syncthreads (compiler's vmcnt(0) drains pair-p DMA)
//     -> issue pair-(p+1) gll (4 x 1 KiB per wave, per-lane source addr)
//     -> ds_read 4 A-frags + 4 B-frags -> 8 MFMAs.
// Loads get a full phase of compute as latency cover at ZERO register cost,
// so occupancy stays at 2 blocks/CU (LDS 70.7 KB, regs ~200).
// Buffer safety: pair p+1's buffer was last read in phase p-1; phase p's
// barrier sits between those reads and the new DMA writes.
// ---------------------------------------------------------------------------
__global__ __launch_bounds__(256, 2)
void ecm_main(const float* __restrict__ cen, const uint16_t* __restrict__ cenT,
              const uint16_t* __restrict__ W3bf, float* __restrict__ out) {
    const int tid = threadIdx.x;
    const int wv = tid >> 6, lane = tid & 63, col = lane & 31, kh = lane >> 5;
    const int x0 = blockIdx.x * XT, y0 = blockIdx.y * YT, b = blockIdx.z;

    __shared__ __align__(16) uint16_t ldsA[YT * XE * CP];   // 35,904 B  (B operand)
    __shared__ __align__(16) uint16_t ldsW[2 * 16 * 512];   // 32,768 B  (A double buffer)
    __shared__ __align__(16) float ldsP[2][64][4];          // ping-pong norm partials (2 KB)

    // g processed in dy-groups; dgOrd[idx] = reference g index, dx = idx%3 - 1.
    const int dgOrd[9] = {0, 1, 2, 7, 8, 3, 6, 5, 4};

    const int fo = lane * 8;          // lane-linear A-frag offset (uint16 units)
    f32x16 finA0 = {}, finA1 = {}, finB0 = {}, finB1 = {};

    #pragma unroll 1
    for (int idx = 0; idx < 9; ++idx) {
        const int g = dgOrd[idx], dg = idx / 3, dx = idx % 3 - 1;

        if (idx % 3 == 0) {
            // All waves passed the previous g's norm barrier => their ldsA reads
            // (which precede it) are done.  Safe to restage without extra barrier;
            // phase-0's __syncthreads below publishes the writes.
            for (int r = 0; r < YT; ++r) {
                const uint4* gs = (const uint4*)(cenT + (((size_t)b * HP + (y0 + dg + r)) * HP + x0) * CP);
                uint4* ls = (uint4*)(ldsA + r * XE * CP);
                for (int c = tid; c < XE * CP / 8; c += 256) ls[c] = gs[c];
            }
        }

        const uint16_t* wg = W3bf + (size_t)g * 65536 + fo;  // per-lane A source base
        const int a0 = (col + dx + 1) * CP + kh * 8;
        const int a1 = a0 + XE * CP;

        // prologue: issue ks-pair 0 into buffer 0 (units u = ksip*8 + t)
        #pragma unroll
        for (int i = 0; i < 4; ++i) {
            int u = wv * 4 + i, ksip = u >> 3, t = u & 7;
            gll16(wg + ((size_t)t * 16 + ksip) * 512, ldsW + u * 512);
        }

        f32x16 aA0 = {}, aA1 = {}, aB0 = {}, aB1 = {};

        #pragma unroll
        for (int p = 0; p < 8; ++p) {
            __syncthreads();   // drains pair-p DMA (implicit vmcnt(0)) + publishes
            if (p < 7) {       // issue pair-(p+1) into the other buffer
                #pragma unroll
                for (int i = 0; i < 4; ++i) {
                    int u = wv * 4 + i, ksip = u >> 3, t = u & 7;
                    gll16(wg + ((size_t)t * 16 + (p + 1) * 2 + ksip) * 512,
                          ldsW + ((p + 1) & 1) * 8192 + u * 512);
                }
            }
            const uint16_t* wb = ldsW + (p & 1) * 8192;
            bf16x8 wa0k0 = *(const bf16x8*)(wb + (0 * 8 + 2 * wv) * 512 + fo);
            bf16x8 wa1k0 = *(const bf16x8*)(wb + (0 * 8 + 2 * wv + 1) * 512 + fo);
            bf16x8 wa0k1 = *(const bf16x8*)(wb + (1 * 8 + 2 * wv) * 512 + fo);
            bf16x8 wa1k1 = *(const bf16x8*)(wb + (1 * 8 + 2 * wv + 1) * 512 + fo);
            const int ko = p * 32;
            bf16x8 b00 = *(const bf16x8*)(ldsA + a0 + ko);
            bf16x8 b10 = *(const bf16x8*)(ldsA + a1 + ko);
            bf16x8 b01 = *(const bf16x8*)(ldsA + a0 + ko + 16);
            bf16x8 b11 = *(const bf16x8*)(ldsA + a1 + ko + 16);
            aA0 = __builtin_amdgcn_mfma_f32_32x32x16_bf16(wa0k0, b00, aA0, 0, 0, 0);
            aB0 = __builtin_amdgcn_mfma_f32_32x32x16_bf16(wa1k0, b00, aB0, 0, 0, 0);
            aA1 = __builtin_amdgcn_mfma_f32_32x32x16_bf16(wa0k0, b10, aA1, 0, 0, 0);
            aB1 = __builtin_amdgcn_mfma_f32_32x32x16_bf16(wa1k0, b10, aB1, 0, 0, 0);
            aA0 = __builtin_amdgcn_mfma_f32_32x32x16_bf16(wa0k1, b01, aA0, 0, 0, 0);
            aB0 = __builtin_amdgcn_mfma_f32_32x32x16_bf16(wa1k1, b01, aB0, 0, 0, 0);
            aA1 = __builtin_amdgcn_mfma_f32_32x32x16_bf16(wa0k1, b11, aA1, 0, 0, 0);
            aB1 = __builtin_amdgcn_mfma_f32_32x32x16_bf16(wa1k1, b11, aB1, 0, 0, 0);
        }

        // Per-position ||Y||^2 partial over this wave's 64 ch (both tiles).
        float s0 = 0.f, s1 = 0.f;
        #pragma unroll
        for (int r = 0; r < 16; ++r) {
            s0 += aA0[r] * aA0[r] + aB0[r] * aB0[r];
            s1 += aA1[r] * aA1[r] + aB1[r] * aB1[r];
        }
        s0 += __shfl_xor(s0, 32, 64);
        s1 += __shfl_xor(s1, 32, 64);
        if (kh == 0) { ldsP[idx & 1][col][wv] = s0; ldsP[idx & 1][32 + col][wv] = s1; }
        __syncthreads();   // norm barrier (ping-pong covers WAR); also fences
                           // ldsA/ldsW reuse across g

        f32x4 pa = *(const f32x4*)&ldsP[idx & 1][col][0];
        f32x4 qa = *(const f32x4*)&ldsP[idx & 1][32 + col][0];
        float n0 = pa[0] + pa[1] + pa[2] + pa[3];
        float n1 = qa[0] + qa[1] + qa[2] + qa[3];
        const float sgn = (g == 8) ? 1.f : -1.f;
        float sc0 = sgn / fmaxf(sqrtf(n0), 1e-12f);
        float sc1 = sgn / fmaxf(sqrtf(n1), 1e-12f);
        #pragma unroll
        for (int r = 0; r < 16; ++r) {
            finA0[r] += aA0[r] * sc0; finB0[r] += aB0[r] * sc0;
            finA1[r] += aA1[r] * sc1; finB1[r] += aB1[r] * sc1;
        }
    }

    // Epilogue: out = fin + cen. D row->ch: (reg&3) + 8*(reg>>2) + 4*kh (+64*wv / +32 tileB).
    #pragma unroll
    for (int r = 0; r < 16; ++r) {
        int chA = wv * 64 + (r & 3) + 8 * (r >> 2) + 4 * kh;
        size_t oA0 = (((size_t)b * CC + chA) * HH + y0) * WW + (x0 + col);
        size_t oA1 = oA0 + WW;
        out[oA0] = finA0[r] + cen[oA0];
        out[oA1] = finA1[r] + cen[oA1];
        size_t oB0 = oA0 + (size_t)32 * HH * WW;
        size_t oB1 = oB0 + WW;
        out[oB0] = finB0[r] + cen[oB0];
        out[oB1] = finB1[r] + cen[oB1];
    }
}

extern "C" void kernel_launch(void* const* d_in, const int* in_sizes, int n_in,
                              void* d_out, int out_size, void* d_ws, size_t ws_size,
                              hipStream_t stream) {
    const float* cen = (const float*)d_in[0];
    // d_in[1] = W1, d_in[2] = W2: dead code (softmax over size-1 axis == 1.0)
    const float* W3 = (const float*)d_in[3];
    float* out = (float*)d_out;

    uint16_t* cenT = (uint16_t*)d_ws;                         // [4][98][98][264] bf16
    const size_t cenT_elems = (size_t)BB * HP * HP * CP;
    uint16_t* W3bf = cenT + cenT_elems;                       // [9][8][16][512] bf16

    zero_halo<<<201, 256, 0, stream>>>(cenT);
    transpose_cen<<<dim3(HH, BB, 2), 256, 0, stream>>>(cen, cenT);
    cvt_w3<<<576, 256, 0, stream>>>(W3, W3bf);
    ecm_main<<<dim3(3, 48, 4), 256, 0, stream>>>(cen, cenT, W3bf, out);
}

// Round 6
// 193.400 us; speedup vs baseline: 1.0871x; 1.0871x over previous
//
#include <hip/hip_runtime.h>
#include <stdint.h>

// Problem constants
#define BB 4
#define CC 256
#define HH 96
#define WW 96
#define HP 98      // halo-padded spatial dim
#define CP 264     // k-stride per x in ush (528 B; measured near-conflict-free b128 frags)
#define XT 32      // x positions per block
#define YT 2       // y rows per block
#define XE 34      // staged x entries (32 + 2 halo)

typedef __bf16 bf16x8 __attribute__((ext_vector_type(8)));
typedef float f32x4 __attribute__((ext_vector_type(4)));
typedef float f32x16 __attribute__((ext_vector_type(16)));
typedef uint32_t u32x4 __attribute__((ext_vector_type(4)));   // clang vector: legal for NT builtins

__device__ __forceinline__ uint16_t f2bf(float f) {
    uint32_t u = __float_as_uint(f);
    u += 0x7FFFu + ((u >> 16) & 1u);   // round-to-nearest-even
    return (uint16_t)(u >> 16);
}

// ---------------------------------------------------------------------------
// Pre-kernel 0: zero only the halo strips of cenT (y=0/97 rows, x=0/97 cols).
// Replaces a 40 MB full-workspace memset (~0.8 MB of writes instead).
// ---------------------------------------------------------------------------
__global__ void zero_halo(uint16_t* __restrict__ cenT) {
    int idx = blockIdx.x * 256 + threadIdx.x;          // over 1552 pos * 33 uint4
    if (idx >= 1552 * 33) return;
    int p = idx / 33, q = idx - p * 33;
    int b = p / 388, s = p - b * 388;
    int y, x;
    if (s < 98)      { y = 0;       x = s; }
    else if (s < 196){ y = 97;      x = s - 98; }
    else if (s < 292){ x = 0;       y = s - 196 + 1; }
    else             { x = 97;      y = s - 292 + 1; }
    size_t o = (((size_t)b * HP + y) * HP + x) * CP + q * 8;
    *(uint4*)(cenT + o) = make_uint4(0u, 0u, 0u, 0u);
}

// ---------------------------------------------------------------------------
// Pre-kernel 1: cen (NCHW fp32) -> cenT [b][hy 98][hx 98][264] bf16 (interior).
// Block = (y, b, c-half): 25.6 KB LDS.
// ---------------------------------------------------------------------------
__global__ void transpose_cen(const float* __restrict__ cen, uint16_t* __restrict__ cenT) {
    const int y = blockIdx.x, b = blockIdx.y, ch = blockIdx.z, tid = threadIdx.x;
    __shared__ uint16_t ldsX[128 * 100];

    #pragma unroll
    for (int i = 0; i < 12; ++i) {
        int f = i * 256 + tid;            // 0..3071: 128 c x 24 xq
        int c = f / 24, xq = f % 24;
        float4 v = *(const float4*)(cen + ((((size_t)b * CC + ch * 128 + c) * HH + y) * WW + xq * 4));
        uint2 pk;
        pk.x = (uint32_t)f2bf(v.x) | ((uint32_t)f2bf(v.y) << 16);
        pk.y = (uint32_t)f2bf(v.z) | ((uint32_t)f2bf(v.w) << 16);
        *(uint2*)(&ldsX[c * 100 + xq * 4]) = pk;
    }
    __syncthreads();
    #pragma unroll
    for (int i = 0; i < 6; ++i) {
        int t = i * 256 + tid;            // 0..1535: 96 x * 16 cq
        int x = t % 96, cq = t / 96;
        uint32_t w0, w1, w2, w3;
        w0 = (uint32_t)ldsX[(cq * 8 + 0) * 100 + x] | ((uint32_t)ldsX[(cq * 8 + 1) * 100 + x] << 16);
        w1 = (uint32_t)ldsX[(cq * 8 + 2) * 100 + x] | ((uint32_t)ldsX[(cq * 8 + 3) * 100 + x] << 16);
        w2 = (uint32_t)ldsX[(cq * 8 + 4) * 100 + x] | ((uint32_t)ldsX[(cq * 8 + 5) * 100 + x] << 16);
        w3 = (uint32_t)ldsX[(cq * 8 + 6) * 100 + x] | ((uint32_t)ldsX[(cq * 8 + 7) * 100 + x] << 16);
        size_t o = (((size_t)b * HP + (y + 1)) * HP + (x + 1)) * CP + ch * 128 + cq * 8;
        *(uint4*)(cenT + o) = make_uint4(w0, w1, w2, w3);
    }
}

// ---------------------------------------------------------------------------
// Pre-kernel 2: W3 [9][256 n][256 k] fp32 -> W3bf [g][t 8][ks 16][m 32][kh 2][8]
// A-frag (32x32x16: lane m holds k = kh*8 + j) for (g,t,ks) = 1 KiB contiguous.
// (R1-proven layout; frags read direct-to-register in ecm_main.)
// ---------------------------------------------------------------------------
__global__ void cvt_w3(const float* __restrict__ W3, uint16_t* __restrict__ W3bf) {
    int e = (blockIdx.x * 256 + threadIdx.x) * 4;   // 0..589823
    int g = e >> 16, n = (e >> 8) & 255, k = e & 255;
    float4 v = *(const float4*)(W3 + e);
    uint2 pk;
    pk.x = (uint32_t)f2bf(v.x) | ((uint32_t)f2bf(v.y) << 16);
    pk.y = (uint32_t)f2bf(v.z) | ((uint32_t)f2bf(v.w) << 16);
    size_t o = (size_t)(((g * 8 + (n >> 5)) * 16 + (k >> 4)) * 512)
             + (n & 31) * 16 + ((k >> 3) & 1) * 8 + (k & 7);
    *(uint2*)(W3bf + o) = pk;
}

// ---------------------------------------------------------------------------
// Main kernel: grid (3 xt, 48 yt, 4 b) = 576 blocks, 256 thr (4 waves).
// Block tile: 64 positions (2 rows x 32 x) x 256 ch; wave wv owns ch-tiles
// (2wv, 2wv+1): per ks-step = 2 A-loads (L2) + 2 B-reads (LDS, each feeding
// 2 MFMAs) + 4 MFMAs on 4 independent acc chains.
// Round-6 = round-5 theory with the NT-builtin type fixed (u32x4 ext-vector):
//  (1) NON-TEMPORAL hints on all streaming traffic (cenT restage loads,
//      epilogue cen loads, out stores) so the 1.125 MB W3bf A-stream stays
//      XCD-L2-resident instead of being evicted to Infinity-Cache latency.
//  (2) A-prefetch depth 2 (qA/qB rotating regs, static indices, +16 VGPR)
//      to cover the remaining ~200cyc L2-hit latency.  B stays 1-deep.
// Norm: 32 in-lane FMA + shfl_xor(32) + ping-pong ldsP -> ONE barrier per g.
// Occupancy: 2 blocks/CU (regs ~228 total incl. acc, LDS 38.4 KB).
// ---------------------------------------------------------------------------
__global__ __launch_bounds__(256, 2)
void ecm_main(const float* __restrict__ cen, const uint16_t* __restrict__ cenT,
              const uint16_t* __restrict__ W3bf, float* __restrict__ out) {
    const int tid = threadIdx.x;
    const int wv = tid >> 6, lane = tid & 63, col = lane & 31, kh = lane >> 5;
    const int x0 = blockIdx.x * XT, y0 = blockIdx.y * YT, b = blockIdx.z;

    __shared__ __align__(16) uint16_t ldsA[YT * XE * CP];   // 35,904 B
    __shared__ __align__(16) float ldsP[2][64][4];          // ping-pong norm partials (2 KB)

    // g processed in dy-groups; dgOrd[idx] = reference g index, dx = idx%3 - 1.
    const int dgOrd[9] = {0, 1, 2, 7, 8, 3, 6, 5, 4};

    // wave owns ch-tiles 2wv and 2wv+1 (adjacent 16-KB A-streams per g)
    const uint16_t* wbA = W3bf + (size_t)(2 * wv) * (16 * 512) + col * 16 + kh * 8;
    f32x16 finA0 = {}, finA1 = {}, finB0 = {}, finB1 = {};

    #pragma unroll 1
    for (int idx = 0; idx < 9; ++idx) {
        const int g = dgOrd[idx], dg = idx / 3, dx = idx % 3 - 1;

        if (idx % 3 == 0) {
            // All waves passed the previous g's barrier => their ldsA reads are
            // done (reads precede each wave's ldsP write, which precedes that
            // barrier). Safe to restage without an extra leading barrier.
            // Non-temporal: cenT is streamed once, must not evict W3bf from L2.
            for (int r = 0; r < YT; ++r) {
                const u32x4* gs = (const u32x4*)(cenT + (((size_t)b * HP + (y0 + dg + r)) * HP + x0) * CP);
                u32x4* ls = (u32x4*)(ldsA + r * XE * CP);
                for (int c = tid; c < XE * CP / 8; c += 256) {
                    u32x4 v = __builtin_nontemporal_load(gs + c);
                    ls[c] = v;
                }
            }
            __syncthreads();
        }

        const uint16_t* wgA = wbA + (size_t)g * 65536;
        const uint16_t* wgB = wgA + 16 * 512;                 // second ch-tile
        const int a0 = (col + dx + 1) * CP + kh * 8;
        const int a1 = a0 + XE * CP;

        f32x16 aA0 = {}, aA1 = {}, aB0 = {}, aB1 = {};

        // A: depth-2 rotating queue (static idx); B: 1-deep (LDS, low latency)
        bf16x8 qA[2], qB[2];
        qA[0] = *(const bf16x8*)(wgA);
        qB[0] = *(const bf16x8*)(wgB);
        qA[1] = *(const bf16x8*)(wgA + 512);
        qB[1] = *(const bf16x8*)(wgB + 512);
        bf16x8 b0 = *(const bf16x8*)(ldsA + a0);
        bf16x8 b1 = *(const bf16x8*)(ldsA + a1);

        #pragma unroll
        for (int ks = 0; ks < 16; ++ks) {
            bf16x8 wa = qA[ks & 1], wb = qB[ks & 1];
            if (ks + 2 < 16) {
                qA[ks & 1] = *(const bf16x8*)(wgA + (ks + 2) * 512);
                qB[ks & 1] = *(const bf16x8*)(wgB + (ks + 2) * 512);
            }
            bf16x8 n0 = b0, n1 = b1;
            if (ks + 1 < 16) {
                n0 = *(const bf16x8*)(ldsA + a0 + (ks + 1) * 16);
                n1 = *(const bf16x8*)(ldsA + a1 + (ks + 1) * 16);
            }
            aA0 = __builtin_amdgcn_mfma_f32_32x32x16_bf16(wa, b0, aA0, 0, 0, 0);
            aB0 = __builtin_amdgcn_mfma_f32_32x32x16_bf16(wb, b0, aB0, 0, 0, 0);
            aA1 = __builtin_amdgcn_mfma_f32_32x32x16_bf16(wa, b1, aA1, 0, 0, 0);
            aB1 = __builtin_amdgcn_mfma_f32_32x32x16_bf16(wb, b1, aB1, 0, 0, 0);
            b0 = n0; b1 = n1;
        }

        // Per-position ||Y||^2 partial over this wave's 64 ch (both tiles).
        float s0 = 0.f, s1 = 0.f;
        #pragma unroll
        for (int r = 0; r < 16; ++r) {
            s0 += aA0[r] * aA0[r] + aB0[r] * aB0[r];
            s1 += aA1[r] * aA1[r] + aB1[r] * aB1[r];
        }
        s0 += __shfl_xor(s0, 32, 64);
        s1 += __shfl_xor(s1, 32, 64);
        if (kh == 0) { ldsP[idx & 1][col][wv] = s0; ldsP[idx & 1][32 + col][wv] = s1; }
        __syncthreads();   // the ONLY barrier per g (ping-pong covers WAR)

        f32x4 pa = *(const f32x4*)&ldsP[idx & 1][col][0];
        f32x4 qa = *(const f32x4*)&ldsP[idx & 1][32 + col][0];
        float n0 = pa[0] + pa[1] + pa[2] + pa[3];
        float n1 = qa[0] + qa[1] + qa[2] + qa[3];
        const float sgn = (g == 8) ? 1.f : -1.f;
        float sc0 = sgn / fmaxf(sqrtf(n0), 1e-12f);
        float sc1 = sgn / fmaxf(sqrtf(n1), 1e-12f);
        #pragma unroll
        for (int r = 0; r < 16; ++r) {
            finA0[r] += aA0[r] * sc0; finB0[r] += aB0[r] * sc0;
            finA1[r] += aA1[r] * sc1; finB1[r] += aB1[r] * sc1;
        }
    }

    // Epilogue: out = fin + cen. D row->ch: (reg&3) + 8*(reg>>2) + 4*kh (+64*wv / +32 tileB).
    // Non-temporal on both cen loads and out stores (pure streaming, 75 MB).
    #pragma unroll
    for (int r = 0; r < 16; ++r) {
        int chA = wv * 64 + (r & 3) + 8 * (r >> 2) + 4 * kh;
        size_t oA0 = (((size_t)b * CC + chA) * HH + y0) * WW + (x0 + col);
        size_t oA1 = oA0 + WW;
        __builtin_nontemporal_store(finA0[r] + __builtin_nontemporal_load(cen + oA0), out + oA0);
        __builtin_nontemporal_store(finA1[r] + __builtin_nontemporal_load(cen + oA1), out + oA1);
        size_t oB0 = oA0 + (size_t)32 * HH * WW;
        size_t oB1 = oB0 + WW;
        __builtin_nontemporal_store(finB0[r] + __builtin_nontemporal_load(cen + oB0), out + oB0);
        __builtin_nontemporal_store(finB1[r] + __builtin_nontemporal_load(cen + oB1), out + oB1);
    }
}

extern "C" void kernel_launch(void* const* d_in, const int* in_sizes, int n_in,
                              void* d_out, int out_size, void* d_ws, size_t ws_size,
                              hipStream_t stream) {
    const float* cen = (const float*)d_in[0];
    // d_in[1] = W1, d_in[2] = W2: dead code (softmax over size-1 axis == 1.0)
    const float* W3 = (const float*)d_in[3];
    float* out = (float*)d_out;

    uint16_t* cenT = (uint16_t*)d_ws;                         // [4][98][98][264] bf16
    const size_t cenT_elems = (size_t)BB * HP * HP * CP;
    uint16_t* W3bf = cenT + cenT_elems;                       // [9][8][16][512] bf16

    zero_halo<<<201, 256, 0, stream>>>(cenT);
    transpose_cen<<<dim3(HH, BB, 2), 256, 0, stream>>>(cen, cenT);
    cvt_w3<<<576, 256, 0, stream>>>(W3, W3bf);
    ecm_main<<<dim3(3, 48, 4), 256, 0, stream>>>(cen, cenT, W3bf, out);
}

// Round 7
// 171.588 us; speedup vs baseline: 1.2253x; 1.1271x over previous
//
#include <hip/hip_runtime.h>
#include <stdint.h>

// Problem constants
#define BB 4
#define CC 256
#define HH 96
#define WW 96
#define HP 98      // halo-padded spatial dim
#define CP 264     // k-stride per x in ush (528 B; measured near-conflict-free b128 frags)
#define XT 32      // x positions per block
#define YT 2       // y rows per block
#define XE 34      // staged x entries (32 + 2 halo)

typedef __bf16 bf16x8 __attribute__((ext_vector_type(8)));
typedef __bf16 bf16x16 __attribute__((ext_vector_type(16)));
typedef float f32x4 __attribute__((ext_vector_type(4)));
typedef float f32x16 __attribute__((ext_vector_type(16)));

__device__ __forceinline__ uint16_t f2bf(float f) {
    uint32_t u = __float_as_uint(f);
    u += 0x7FFFu + ((u >> 16) & 1u);   // round-to-nearest-even
    return (uint16_t)(u >> 16);
}

// ---------------------------------------------------------------------------
// Pre-kernel 0: zero only the halo strips of cenT (y=0/97 rows, x=0/97 cols).
// Replaces a 40 MB full-workspace memset (~0.8 MB of writes instead).
// ---------------------------------------------------------------------------
__global__ void zero_halo(uint16_t* __restrict__ cenT) {
    int idx = blockIdx.x * 256 + threadIdx.x;          // over 1552 pos * 33 uint4
    if (idx >= 1552 * 33) return;
    int p = idx / 33, q = idx - p * 33;
    int b = p / 388, s = p - b * 388;
    int y, x;
    if (s < 98)      { y = 0;       x = s; }
    else if (s < 196){ y = 97;      x = s - 98; }
    else if (s < 292){ x = 0;       y = s - 196 + 1; }
    else             { x = 97;      y = s - 292 + 1; }
    size_t o = (((size_t)b * HP + y) * HP + x) * CP + q * 8;
    *(uint4*)(cenT + o) = make_uint4(0u, 0u, 0u, 0u);
}

// ---------------------------------------------------------------------------
// Pre-kernel 1: cen (NCHW fp32) -> cenT [b][hy 98][hx 98][264] bf16 (interior).
// Block = (y, b, c-half): 25.6 KB LDS.
// ---------------------------------------------------------------------------
__global__ void transpose_cen(const float* __restrict__ cen, uint16_t* __restrict__ cenT) {
    const int y = blockIdx.x, b = blockIdx.y, ch = blockIdx.z, tid = threadIdx.x;
    __shared__ uint16_t ldsX[128 * 100];

    #pragma unroll
    for (int i = 0; i < 12; ++i) {
        int f = i * 256 + tid;            // 0..3071: 128 c x 24 xq
        int c = f / 24, xq = f % 24;
        float4 v = *(const float4*)(cen + ((((size_t)b * CC + ch * 128 + c) * HH + y) * WW + xq * 4));
        uint2 pk;
        pk.x = (uint32_t)f2bf(v.x) | ((uint32_t)f2bf(v.y) << 16);
        pk.y = (uint32_t)f2bf(v.z) | ((uint32_t)f2bf(v.w) << 16);
        *(uint2*)(&ldsX[c * 100 + xq * 4]) = pk;
    }
    __syncthreads();
    #pragma unroll
    for (int i = 0; i < 6; ++i) {
        int t = i * 256 + tid;            // 0..1535: 96 x * 16 cq
        int x = t % 96, cq = t / 96;
        uint32_t w0, w1, w2, w3;
        w0 = (uint32_t)ldsX[(cq * 8 + 0) * 100 + x] | ((uint32_t)ldsX[(cq * 8 + 1) * 100 + x] << 16);
        w1 = (uint32_t)ldsX[(cq * 8 + 2) * 100 + x] | ((uint32_t)ldsX[(cq * 8 + 3) * 100 + x] << 16);
        w2 = (uint32_t)ldsX[(cq * 8 + 4) * 100 + x] | ((uint32_t)ldsX[(cq * 8 + 5) * 100 + x] << 16);
        w3 = (uint32_t)ldsX[(cq * 8 + 6) * 100 + x] | ((uint32_t)ldsX[(cq * 8 + 7) * 100 + x] << 16);
        size_t o = (((size_t)b * HP + (y + 1)) * HP + (x + 1)) * CP + ch * 128 + cq * 8;
        *(uint4*)(cenT + o) = make_uint4(w0, w1, w2, w3);
    }
}

// ---------------------------------------------------------------------------
// Pre-kernel 2: W3 [9][256 n][256 k] fp32 -> W3bf [g][t 8][ks 16][m 32][kh 2][8]
// A-frag (32x32x16: lane m holds k = kh*8 + j) for (g,t,ks) = 1 KiB contiguous.
// (R1-proven layout; frags read direct-to-register in ecm_main.)
// ---------------------------------------------------------------------------
__global__ void cvt_w3(const float* __restrict__ W3, uint16_t* __restrict__ W3bf) {
    int e = (blockIdx.x * 256 + threadIdx.x) * 4;   // 0..589823
    int g = e >> 16, n = (e >> 8) & 255, k = e & 255;
    float4 v = *(const float4*)(W3 + e);
    uint2 pk;
    pk.x = (uint32_t)f2bf(v.x) | ((uint32_t)f2bf(v.y) << 16);
    pk.y = (uint32_t)f2bf(v.z) | ((uint32_t)f2bf(v.w) << 16);
    size_t o = (size_t)(((g * 8 + (n >> 5)) * 16 + (k >> 4)) * 512)
             + (n & 31) * 16 + ((k >> 3) & 1) * 8 + (k & 7);
    *(uint2*)(W3bf + o) = pk;
}

// ---------------------------------------------------------------------------
// Main kernel: grid (3 xt, 48 yt, 4 b) = 576 blocks, 256 thr (4 waves).
// Block tile: 64 positions (2 rows x 32 x) x 256 ch; wave wv owns ch-tiles
// (2wv, 2wv+1): per ks-step = 2 A-loads + 2 B-reads (LDS) + 4 MFMAs.
// Round-7 vs the 83-us R1 kernel (L3-latency diagnosis, reg-cliff lesson):
//  (1) fin accumulators in PACKED BF16 (32 regs instead of 64): elements are
//      sums of <=9 unit-normalized terms (|e| ~ 0.5), so bf16 accumulation
//      adds ~0.005 abs error (threshold 0.108).  Frees 32 regs of the
//      2-waves/SIMD budget that R2/R6 blew.
//  (2) DEPTH-4 rotating A-prefetch (qA/qB, static ks&3 indices): cover ~4
//      iteration-slots ~ 700cyc >= Infinity-Cache hit latency, so the A
//      stall that set the 615-cyc/iter pace disappears.  Total regs
//      ~110 arch + 64 acc = ~174 -> still 2 blocks/CU.
//  (3) s_setprio(1) around the MFMA quad (waves are unsynced between per-g
//      barriers -> role diversity for the CU scheduler to arbitrate).
// Norm: 32 in-lane FMA + shfl_xor(32) + ping-pong ldsP -> ONE barrier per g.
// ---------------------------------------------------------------------------
__global__ __launch_bounds__(256, 2)
void ecm_main(const float* __restrict__ cen, const uint16_t* __restrict__ cenT,
              const uint16_t* __restrict__ W3bf, float* __restrict__ out) {
    const int tid = threadIdx.x;
    const int wv = tid >> 6, lane = tid & 63, col = lane & 31, kh = lane >> 5;
    const int x0 = blockIdx.x * XT, y0 = blockIdx.y * YT, b = blockIdx.z;

    __shared__ __align__(16) uint16_t ldsA[YT * XE * CP];   // 35,904 B
    __shared__ __align__(16) float ldsP[2][64][4];          // ping-pong norm partials (2 KB)

    // g processed in dy-groups; dgOrd[idx] = reference g index, dx = idx%3 - 1.
    const int dgOrd[9] = {0, 1, 2, 7, 8, 3, 6, 5, 4};

    // wave owns ch-tiles 2wv and 2wv+1 (adjacent 16-KB A-streams per g)
    const uint16_t* wbA = W3bf + (size_t)(2 * wv) * (16 * 512) + col * 16 + kh * 8;
    bf16x16 finA0 = {}, finA1 = {}, finB0 = {}, finB1 = {};   // packed bf16 fin

    #pragma unroll 1
    for (int idx = 0; idx < 9; ++idx) {
        const int g = dgOrd[idx], dg = idx / 3, dx = idx % 3 - 1;

        if (idx % 3 == 0) {
            // All waves passed the previous g's barrier => their ldsA reads are
            // done (reads precede each wave's ldsP write, which precedes that
            // barrier). Safe to restage without an extra leading barrier.
            for (int r = 0; r < YT; ++r) {
                const uint4* gs = (const uint4*)(cenT + (((size_t)b * HP + (y0 + dg + r)) * HP + x0) * CP);
                uint4* ls = (uint4*)(ldsA + r * XE * CP);
                for (int c = tid; c < XE * CP / 8; c += 256) ls[c] = gs[c];
            }
            __syncthreads();
        }

        const uint16_t* wgA = wbA + (size_t)g * 65536;
        const uint16_t* wgB = wgA + 16 * 512;                 // second ch-tile
        const int a0 = (col + dx + 1) * CP + kh * 8;
        const int a1 = a0 + XE * CP;

        f32x16 aA0 = {}, aA1 = {}, aB0 = {}, aB1 = {};

        // A: depth-4 rotating queue (static ks&3 idx); B: 1-deep (LDS latency
        // covered by 2-wave overlap + MFMA issue).
        bf16x8 qA[4], qB[4];
        #pragma unroll
        for (int i = 0; i < 4; ++i) {
            qA[i] = *(const bf16x8*)(wgA + i * 512);
            qB[i] = *(const bf16x8*)(wgB + i * 512);
        }
        bf16x8 b0 = *(const bf16x8*)(ldsA + a0);
        bf16x8 b1 = *(const bf16x8*)(ldsA + a1);

        #pragma unroll
        for (int ks = 0; ks < 16; ++ks) {
            bf16x8 wa = qA[ks & 3], wb = qB[ks & 3];
            if (ks + 4 < 16) {
                qA[ks & 3] = *(const bf16x8*)(wgA + (ks + 4) * 512);
                qB[ks & 3] = *(const bf16x8*)(wgB + (ks + 4) * 512);
            }
            bf16x8 n0 = b0, n1 = b1;
            if (ks + 1 < 16) {
                n0 = *(const bf16x8*)(ldsA + a0 + (ks + 1) * 16);
                n1 = *(const bf16x8*)(ldsA + a1 + (ks + 1) * 16);
            }
            __builtin_amdgcn_s_setprio(1);
            aA0 = __builtin_amdgcn_mfma_f32_32x32x16_bf16(wa, b0, aA0, 0, 0, 0);
            aB0 = __builtin_amdgcn_mfma_f32_32x32x16_bf16(wb, b0, aB0, 0, 0, 0);
            aA1 = __builtin_amdgcn_mfma_f32_32x32x16_bf16(wa, b1, aA1, 0, 0, 0);
            aB1 = __builtin_amdgcn_mfma_f32_32x32x16_bf16(wb, b1, aB1, 0, 0, 0);
            __builtin_amdgcn_s_setprio(0);
            b0 = n0; b1 = n1;
        }

        // Per-position ||Y||^2 partial over this wave's 64 ch (both tiles).
        float s0 = 0.f, s1 = 0.f;
        #pragma unroll
        for (int r = 0; r < 16; ++r) {
            s0 += aA0[r] * aA0[r] + aB0[r] * aB0[r];
            s1 += aA1[r] * aA1[r] + aB1[r] * aB1[r];
        }
        s0 += __shfl_xor(s0, 32, 64);
        s1 += __shfl_xor(s1, 32, 64);
        if (kh == 0) { ldsP[idx & 1][col][wv] = s0; ldsP[idx & 1][32 + col][wv] = s1; }
        __syncthreads();   // the ONLY barrier per g (ping-pong covers WAR)

        f32x4 pa = *(const f32x4*)&ldsP[idx & 1][col][0];
        f32x4 qa = *(const f32x4*)&ldsP[idx & 1][32 + col][0];
        float n0 = pa[0] + pa[1] + pa[2] + pa[3];
        float n1 = qa[0] + qa[1] + qa[2] + qa[3];
        const float sgn = (g == 8) ? 1.f : -1.f;
        float sc0 = sgn / fmaxf(sqrtf(n0), 1e-12f);
        float sc1 = sgn / fmaxf(sqrtf(n1), 1e-12f);
        #pragma unroll
        for (int r = 0; r < 16; ++r) {
            finA0[r] = (__bf16)((float)finA0[r] + aA0[r] * sc0);
            finB0[r] = (__bf16)((float)finB0[r] + aB0[r] * sc0);
            finA1[r] = (__bf16)((float)finA1[r] + aA1[r] * sc1);
            finB1[r] = (__bf16)((float)finB1[r] + aB1[r] * sc1);
        }
    }

    // Epilogue: out = fin + cen. D row->ch: (reg&3) + 8*(reg>>2) + 4*kh (+64*wv / +32 tileB).
    #pragma unroll
    for (int r = 0; r < 16; ++r) {
        int chA = wv * 64 + (r & 3) + 8 * (r >> 2) + 4 * kh;
        size_t oA0 = (((size_t)b * CC + chA) * HH + y0) * WW + (x0 + col);
        size_t oA1 = oA0 + WW;
        out[oA0] = (float)finA0[r] + cen[oA0];
        out[oA1] = (float)finA1[r] + cen[oA1];
        size_t oB0 = oA0 + (size_t)32 * HH * WW;
        size_t oB1 = oB0 + WW;
        out[oB0] = (float)finB0[r] + cen[oB0];
        out[oB1] = (float)finB1[r] + cen[oB1];
    }
}

extern "C" void kernel_launch(void* const* d_in, const int* in_sizes, int n_in,
                              void* d_out, int out_size, void* d_ws, size_t ws_size,
                              hipStream_t stream) {
    const float* cen = (const float*)d_in[0];
    // d_in[1] = W1, d_in[2] = W2: dead code (softmax over size-1 axis == 1.0)
    const float* W3 = (const float*)d_in[3];
    float* out = (float*)d_out;

    uint16_t* cenT = (uint16_t*)d_ws;                         // [4][98][98][264] bf16
    const size_t cenT_elems = (size_t)BB * HP * HP * CP;
    uint16_t* W3bf = cenT + cenT_elems;                       // [9][8][16][512] bf16

    zero_halo<<<201, 256, 0, stream>>>(cenT);
    transpose_cen<<<dim3(HH, BB, 2), 256, 0, stream>>>(cen, cenT);
    cvt_w3<<<576, 256, 0, stream>>>(W3, W3bf);
    ecm_main<<<dim3(3, 48, 4), 256, 0, stream>>>(cen, cenT, W3bf, out);
}